// Round 2
// baseline (57.126 us; speedup 1.0000x reference)
//
#include <hip/hip_runtime.h>

constexpr int N_ = 16, L_ = 196, D_ = 1024, T_ = 32;
constexpr int GRID = 256;
constexpr int ROWS = N_ * L_;  // 3136

__global__ __launch_bounds__(256) void fused_kernel(const float* __restrict__ img,
                                                    const float* __restrict__ qes,
                                                    const float* __restrict__ w,
                                                    float* __restrict__ out,
                                                    float* __restrict__ scores,
                                                    unsigned* __restrict__ counter) {
    const int tid = threadIdx.x, b = blockIdx.x;
    const int lane = tid & 63, wv = tid >> 6;

    // ---- Phase 1: scores[r] = dot(img[r,:], w) for r = b + k*GRID ----
    const float4* w4 = reinterpret_cast<const float4*>(w);
    const float4 wf0 = w4[lane], wf1 = w4[lane + 64], wf2 = w4[lane + 128], wf3 = w4[lane + 192];
    for (int k = wv; k < 13; k += 4) {  // one row per wave per step
        const int r = b + k * GRID;
        if (r >= ROWS) break;
        const float4* row = reinterpret_cast<const float4*>(img + (size_t)r * D_);
        const float4 a0 = row[lane], a1 = row[lane + 64], a2 = row[lane + 128], a3 = row[lane + 192];
        float s = a0.x * wf0.x + a0.y * wf0.y + a0.z * wf0.z + a0.w * wf0.w;
        s += a1.x * wf1.x + a1.y * wf1.y + a1.z * wf1.z + a1.w * wf1.w;
        s += a2.x * wf2.x + a2.y * wf2.y + a2.z * wf2.z + a2.w * wf2.w;
        s += a3.x * wf3.x + a3.y * wf3.y + a3.z * wf3.z + a3.w * wf3.w;
        #pragma unroll
        for (int off = 32; off > 0; off >>= 1) s += __shfl_xor(s, off);
        if (lane == 0) scores[r] = s;
    }

    // ---- Grid barrier (device-scope): counter zeroed by hipMemsetAsync each call ----
    __threadfence();
    __syncthreads();
    if (tid == 0) {
        atomicAdd(counter, 1u);
        while (atomicAdd(counter, 0u) < (unsigned)GRID) __builtin_amdgcn_s_sleep(2);
    }
    __syncthreads();
    __threadfence();

    // ---- Phase 2: block b -> n = b>>4, d-chunk = (b&15)*64 ----
    const int n = b >> 4, dbase = (b & 15) * 64;

    __shared__ float p[L_];
    __shared__ float red[8];
    float v = (tid < L_) ? scores[n * L_ + tid] : -INFINITY;
    float m = v;
    #pragma unroll
    for (int off = 32; off > 0; off >>= 1) m = fmaxf(m, __shfl_xor(m, off));
    if (lane == 0) red[wv] = m;
    __syncthreads();
    const float bm = fmaxf(fmaxf(red[0], red[1]), fmaxf(red[2], red[3]));
    float e = (tid < L_) ? __expf(v - bm) : 0.0f;
    float s2 = e;
    #pragma unroll
    for (int off = 32; off > 0; off >>= 1) s2 += __shfl_xor(s2, off);
    if (lane == 0) red[4 + wv] = s2;
    __syncthreads();
    const float bs = red[4] + red[5] + red[6] + red[7];
    if (tid < L_) p[tid] = e / bs;
    __syncthreads();

    // ctx[d] = sum_l p[l]*img[n,l,d]; 4 waves split L, 64 lanes cover d-chunk
    const float* imgn = img + (size_t)n * L_ * D_ + dbase;
    float acc = 0.0f;
    for (int l = wv; l < L_; l += 4)
        acc = fmaf(p[l], imgn[(size_t)l * D_ + lane], acc);

    __shared__ float ctxs[4][64];
    ctxs[wv][lane] = acc;
    __syncthreads();
    __shared__ float ctx[64];
    if (tid < 64) ctx[tid] = ctxs[0][tid] + ctxs[1][tid] + ctxs[2][tid] + ctxs[3][tid];
    __syncthreads();

    const float c = ctx[lane];
    const float* qn = qes + (size_t)n * T_ * D_ + dbase;
    float* on = out + (size_t)n * T_ * D_ + dbase;
    #pragma unroll
    for (int t = wv; t < T_; t += 4)
        on[(size_t)t * D_ + lane] = qn[(size_t)t * D_ + lane] + c;
}

extern "C" void kernel_launch(void* const* d_in, const int* in_sizes, int n_in,
                              void* d_out, int out_size, void* d_ws, size_t ws_size,
                              hipStream_t stream) {
    const float* img = (const float*)d_in[0];   // [N, L, D]
    const float* qes = (const float*)d_in[1];   // [N, T, D]
    const float* w   = (const float*)d_in[2];   // [D]
    float* out = (float*)d_out;                 // [N, T, D]
    float* scores = (float*)d_ws;               // ROWS floats
    unsigned* counter = (unsigned*)((char*)d_ws + ROWS * sizeof(float));

    hipMemsetAsync(counter, 0, sizeof(unsigned), stream);  // graph-capturable memset node
    fused_kernel<<<GRID, 256, 0, stream>>>(img, qes, w, out, scores, counter);
}

// Round 3
// 17.240 us; speedup vs baseline: 3.3135x; 3.3135x over previous
//
#include <hip/hip_runtime.h>

constexpr int N_ = 16, L_ = 196, D_ = 1024, T_ = 32;

// Kernel 1: scores[n*L + l] = dot(img[n,l,:], w)
// grid (L, N), 256 threads; each thread one float4 (256*4 = 1024 = D)
__global__ __launch_bounds__(256) void scores_kernel(const float* __restrict__ img,
                                                     const float* __restrict__ w,
                                                     float* __restrict__ scores) {
    const int l = blockIdx.x, n = blockIdx.y;
    const int tid = threadIdx.x;
    const float4* imgrow = reinterpret_cast<const float4*>(img + (size_t)(n * L_ + l) * D_);
    const float4* w4 = reinterpret_cast<const float4*>(w);
    float4 a = imgrow[tid];
    float4 b = w4[tid];
    float s = a.x * b.x + a.y * b.y + a.z * b.z + a.w * b.w;
    #pragma unroll
    for (int off = 32; off > 0; off >>= 1) s += __shfl_xor(s, off);
    __shared__ float red[4];
    const int wave = tid >> 6, lane = tid & 63;
    if (lane == 0) red[wave] = s;
    __syncthreads();
    if (tid == 0) scores[n * L_ + l] = red[0] + red[1] + red[2] + red[3];
}

// Kernel 2: grid (16 d-chunks, 16 n) = 256 blocks, 256 threads.
// Each block: redundant softmax over L (196 values, L2-hot), then
// ctx[d] = sum_l p[l]*img[n,l,d] for its 64-wide d slice (4 waves split L),
// then out[n,t,d] = qes[n,t,d] + ctx[d] for all 32 t.
__global__ __launch_bounds__(256) void ctx_kernel(const float* __restrict__ img,
                                                  const float* __restrict__ qes,
                                                  const float* __restrict__ scores,
                                                  float* __restrict__ out) {
    const int n = blockIdx.y;
    const int dbase = blockIdx.x * 64;
    const int tid = threadIdx.x;
    const int lane = tid & 63, wv = tid >> 6;

    __shared__ float p[L_];
    __shared__ float red[8];

    float v = (tid < L_) ? scores[n * L_ + tid] : -INFINITY;
    float m = v;
    #pragma unroll
    for (int off = 32; off > 0; off >>= 1) m = fmaxf(m, __shfl_xor(m, off));
    if (lane == 0) red[wv] = m;
    __syncthreads();
    const float bm = fmaxf(fmaxf(red[0], red[1]), fmaxf(red[2], red[3]));
    float e = (tid < L_) ? __expf(v - bm) : 0.0f;
    float s = e;
    #pragma unroll
    for (int off = 32; off > 0; off >>= 1) s += __shfl_xor(s, off);
    if (lane == 0) red[4 + wv] = s;
    __syncthreads();
    const float bs = red[4] + red[5] + red[6] + red[7];
    if (tid < L_) p[tid] = e / bs;
    __syncthreads();

    // ctx over L: 4 waves stride L, 64 lanes cover the d slice
    const float* imgn = img + (size_t)n * L_ * D_ + dbase;
    float acc = 0.0f;
    for (int l = wv; l < L_; l += 4)
        acc = fmaf(p[l], imgn[(size_t)l * D_ + lane], acc);

    __shared__ float ctxs[4][64];
    ctxs[wv][lane] = acc;
    __syncthreads();
    __shared__ float ctx[64];
    if (tid < 64) ctx[tid] = ctxs[0][tid] + ctxs[1][tid] + ctxs[2][tid] + ctxs[3][tid];
    __syncthreads();

    const float c = ctx[lane];
    const float* qn = qes + (size_t)n * T_ * D_ + dbase;
    float* on = out + (size_t)n * T_ * D_ + dbase;
    #pragma unroll
    for (int t = wv; t < T_; t += 4)
        on[(size_t)t * D_ + lane] = qn[(size_t)t * D_ + lane] + c;
}

extern "C" void kernel_launch(void* const* d_in, const int* in_sizes, int n_in,
                              void* d_out, int out_size, void* d_ws, size_t ws_size,
                              hipStream_t stream) {
    const float* img = (const float*)d_in[0];   // [N, L, D]
    const float* qes = (const float*)d_in[1];   // [N, T, D]
    const float* w   = (const float*)d_in[2];   // [D]
    float* out = (float*)d_out;                 // [N, T, D]
    float* scores = (float*)d_ws;               // N*L floats

    scores_kernel<<<dim3(L_, N_), 256, 0, stream>>>(img, w, scores);
    ctx_kernel<<<dim3(D_ / 64, N_), 256, 0, stream>>>(img, qes, scores, out);
}